// Round 1
// 1471.253 us; speedup vs baseline: 1.0520x; 1.0520x over previous
//
#include <hip/hip_runtime.h>
#include <cstdint>
#include <cstddef>

#define TLEN 512
#define BATCH 1000
#define NEVS 102400   // events per source
#define HID 64

__device__ __forceinline__ float fast_rcp(float x) {
#if __has_builtin(__builtin_amdgcn_rcpf)
    return __builtin_amdgcn_rcpf(x);
#else
    return 1.0f / x;
#endif
}
__device__ __forceinline__ float sigm(float x) { return fast_rcp(1.0f + __expf(-x)); }
__device__ __forceinline__ float tanh_f(float x) { return fmaf(2.0f, sigm(2.0f * x), -1.0f); }

// Wave-wide sum, broadcast as uniform value.
// rocPRIM gfx9 pattern: row_shr 1/2/4/8 + row_bcast15 + row_bcast31, sum lands in
// lane 63, then readlane -> SGPR (short VALU chain instead of 6 ds-swizzles).
__device__ __forceinline__ float wave_sum_bcast(float x) {
#if __has_builtin(__builtin_amdgcn_update_dpp) && __has_builtin(__builtin_amdgcn_readlane)
    x += __int_as_float(__builtin_amdgcn_update_dpp(0, __float_as_int(x), 0x111, 0xf, 0xf, true)); // row_shr:1
    x += __int_as_float(__builtin_amdgcn_update_dpp(0, __float_as_int(x), 0x112, 0xf, 0xf, true)); // row_shr:2
    x += __int_as_float(__builtin_amdgcn_update_dpp(0, __float_as_int(x), 0x114, 0xf, 0xf, true)); // row_shr:4
    x += __int_as_float(__builtin_amdgcn_update_dpp(0, __float_as_int(x), 0x118, 0xf, 0xf, true)); // row_shr:8
    x += __int_as_float(__builtin_amdgcn_update_dpp(0, __float_as_int(x), 0x142, 0xa, 0xf, true)); // row_bcast:15 -> rows 1,3
    x += __int_as_float(__builtin_amdgcn_update_dpp(0, __float_as_int(x), 0x143, 0xc, 0xf, true)); // row_bcast:31 -> rows 2,3
    return __int_as_float(__builtin_amdgcn_readlane(__float_as_int(x), 63));
#else
#pragma unroll
    for (int off = 1; off < 64; off <<= 1) x += __shfl_xor(x, off, 64);
    return x;
#endif
}

// ===========================================================================
// Composed projection: W'[row][col], row = (src, j) [130 rows], col = dir*256+r.
// row j<IND: W_src[j] . Wih0[col]; row j==IND: b_src . Wih0[col] + bih+bhh.
// ===========================================================================
__global__ __launch_bounds__(512) void compose_kernel(
    const float* __restrict__ W0, const float* __restrict__ B0,
    const float* __restrict__ W1, const float* __restrict__ B1,
    const float* __restrict__ W2, const float* __restrict__ B2,
    const float* __restrict__ W3, const float* __restrict__ B3,
    const float* __restrict__ W4, const float* __restrict__ B4,
    const float* __restrict__ Wih, const float* __restrict__ bih,
    const float* __restrict__ bhh, float* __restrict__ wp)
{
    const int col = threadIdx.x;   // 0..511 == dir*256 + r == Wih row index
    const int row = blockIdx.x;    // 0..129
    const float* srcW; const float* srcB; int base, IND;
    if (row < 9)        { srcW = W0; srcB = B0; base = 0;   IND = 8;  }
    else if (row < 27)  { srcW = W1; srcB = B1; base = 9;   IND = 17; }
    else if (row < 53)  { srcW = W2; srcB = B2; base = 27;  IND = 25; }
    else if (row < 120) { srcW = W3; srcB = B3; base = 53;  IND = 66; }
    else                { srcW = W4; srcB = B4; base = 120; IND = 9;  }
    const int j = row - base;
    const float* xrow = (j < IND) ? (srcW + (size_t)j * 64) : srcB;
    const float* wr = Wih + (size_t)col * 64;
    float acc = 0.0f;
#pragma unroll
    for (int h2 = 0; h2 < 64; ++h2) acc = fmaf(xrow[h2], wr[h2], acc);
    if (j == IND) acc += bih[col] + bhh[col];
    wp[(size_t)row * 512 + col] = acc;
}

// ===========================================================================
// Time-chunked projection: for events with ti in this chunk's range, write
// g_pre rows (256 cols = one direction) into gf/gb chunk buffers.
// Coalesced vector scan -> LDS queue -> block-uniform gather per event,
// 2 events in flight to overlap scalar-load latency.
// ===========================================================================
template<int NNUM, int NCAT>
__device__ __forceinline__ void project_src(
    const float* __restrict__ num, const int* __restrict__ cat,
    const float* __restrict__ tab, const int* __restrict__ bi,
    const int* __restrict__ ti, const float* __restrict__ wrows,
    float* __restrict__ gdst, int dir, int lo, int hi, int tcm,
    int* qcnt, int* queue)
{
    constexpr int IND = NCAT * 8 + NNUM;
    const int tid = threadIdx.x;
    const int col = dir * 256 + tid;
    float wcol[IND];
#pragma unroll
    for (int j = 0; j < IND; ++j) wcol[j] = wrows[(size_t)j * 512 + col];
    const float bcol = wrows[(size_t)IND * 512 + col];

    const int S = gridDim.x;
    const int per = (NEVS + S - 1) / S;
    const int e0 = blockIdx.x * per;
    const int e1 = (e0 + per < NEVS) ? (e0 + per) : NEVS;

    for (int base = e0; base < e1; base += 256) {
        if (tid == 0) *qcnt = 0;
        __syncthreads();
        {
            const int ev = base + tid;
            if (ev < e1) {
                const int t = ti[ev];
                if (t >= lo && t < hi) {
                    const int s = atomicAdd(qcnt, 1);
                    queue[s] = ev;
                }
            }
        }
        __syncthreads();
        const int n = *qcnt;
        for (int i = 0; i < n; i += 2) {
            const int eA = __builtin_amdgcn_readfirstlane(queue[i]);
            const bool two = (i + 1 < n);
            const int eB = two ? __builtin_amdgcn_readfirstlane(queue[i + 1]) : eA;
            float accA = bcol, accB = bcol;
#pragma unroll
            for (int c0 = 0; c0 < NCAT; ++c0) {
                const int ia = cat[eA * NCAT + c0];
                const int ib = cat[eB * NCAT + c0];
                const float* ta = tab + (size_t)ia * 8;
                const float* tb = tab + (size_t)ib * 8;
#pragma unroll
                for (int u = 0; u < 8; ++u) {
                    accA = fmaf(ta[u], wcol[c0 * 8 + u], accA);
                    accB = fmaf(tb[u], wcol[c0 * 8 + u], accB);
                }
            }
#pragma unroll
            for (int u = 0; u < NNUM; ++u) {
                accA = fmaf(num[(size_t)eA * NNUM + u], wcol[NCAT * 8 + u], accA);
                accB = fmaf(num[(size_t)eB * NNUM + u], wcol[NCAT * 8 + u], accB);
            }
            {
                const int tA = ti[eA], pA = bi[eA];
                const int lA = dir ? (hi - 1 - tA) : (tA - lo);
                gdst[((size_t)pA * tcm + lA) * 256 + tid] = accA;
            }
            if (two) {
                const int tB = ti[eB], pB = bi[eB];
                const int lB = dir ? (hi - 1 - tB) : (tB - lo);
                gdst[((size_t)pB * tcm + lB) * 256 + tid] = accB;
            }
        }
        __syncthreads();
    }
}

__global__ __launch_bounds__(256) void project_chunk_kernel(
    const float* __restrict__ ccba_num, const int* __restrict__ ccba_bi, const int* __restrict__ ccba_ti,
    const float* __restrict__ cdtx_num, const int* __restrict__ cdtx_cat, const float* __restrict__ cdtx_tab,
    const int* __restrict__ cdtx_bi, const int* __restrict__ cdtx_ti,
    const float* __restrict__ cust_num, const int* __restrict__ cust_cat, const float* __restrict__ cust_tab,
    const int* __restrict__ cust_bi, const int* __restrict__ cust_ti,
    const float* __restrict__ dp_num, const int* __restrict__ dp_cat, const float* __restrict__ dp_tab,
    const int* __restrict__ dp_bi, const int* __restrict__ dp_ti,
    const float* __restrict__ remit_num, const int* __restrict__ remit_cat, const float* __restrict__ remit_tab,
    const int* __restrict__ remit_bi, const int* __restrict__ remit_ti,
    const float* __restrict__ wp, float* __restrict__ gf, float* __restrict__ gb,
    int f0, int len, int tcm)
{
    __shared__ int qcnt;
    __shared__ int queue[256];
    const int dir = blockIdx.y & 1;
    const int src = blockIdx.y >> 1;
    const int lo = dir ? (TLEN - f0 - len) : f0;   // bwd chunk is the mirrored range
    const int hi = lo + len;
    float* gdst = dir ? gb : gf;
    switch (src) {
        case 0: project_src<8, 0>(ccba_num, nullptr, nullptr, ccba_bi, ccba_ti, wp + 0 * 512,   gdst, dir, lo, hi, tcm, &qcnt, queue); break;
        case 1: project_src<1, 2>(cdtx_num, cdtx_cat, cdtx_tab, cdtx_bi, cdtx_ti, wp + 9 * 512,  gdst, dir, lo, hi, tcm, &qcnt, queue); break;
        case 2: project_src<1, 3>(cust_num, cust_cat, cust_tab, cust_bi, cust_ti, wp + 27 * 512, gdst, dir, lo, hi, tcm, &qcnt, queue); break;
        case 3: project_src<2, 8>(dp_num,   dp_cat,   dp_tab,   dp_bi,   dp_ti,   wp + 53 * 512, gdst, dir, lo, hi, tcm, &qcnt, queue); break;
        default: project_src<1, 1>(remit_num, remit_cat, remit_tab, remit_bi, remit_ti, wp + 120 * 512, gdst, dir, lo, hi, tcm, &qcnt, queue); break;
    }
}

// ===========================================================================
// Layer-0 recurrence over the precomputed chunk: one wave per (b,dir),
// lane = cell. (h,c) state carried across chunk launches in workspace.
// ===========================================================================
__global__ __launch_bounds__(256) void rec_chunk_kernel(
    const float* __restrict__ gf, const float* __restrict__ gb,
    const float* __restrict__ Whh, const float* __restrict__ Whr,
    float* __restrict__ h0, float* __restrict__ hs, float* __restrict__ cs,
    int f0, int len, int tcm, int first)
{
    const int wv = threadIdx.x >> 6, lane = threadIdx.x & 63;
    const int p = blockIdx.x * 4 + wv;          // 0..1999
    const int b = p >> 1, dir = p & 1;

    float whh4[4];
#pragma unroll
    for (int k = 0; k < 4; ++k) whh4[k] = Whh[dir * 256 + k * 64 + lane];
    const float whr = Whr[dir * HID + lane];

    const float* g = (dir ? gb : gf) + (size_t)b * tcm * 256 + lane;
    float* h0p = h0 + (size_t)b * TLEN * 2 + dir;

    float h, c;
    if (first) { h = 0.0f; c = 0.0f; }
    else       { h = hs[p]; c = cs[(size_t)p * 64 + lane]; }

    float A[4];
#pragma unroll
    for (int k = 0; k < 4; ++k) A[k] = g[k * 64];

    for (int s = 0; s < len; ++s) {
        float Nx[4];
        const int sn = (s + 1 < len) ? (s + 1) : s;   // clamp; value unused past end
        const float* gn = g + (size_t)sn * 256;
#pragma unroll
        for (int k = 0; k < 4; ++k) Nx[k] = gn[k * 64];

        const float gi = fmaf(whh4[0], h, A[0]);
        const float gfv = fmaf(whh4[1], h, A[1]);
        const float gg = fmaf(whh4[2], h, A[2]);
        const float go = fmaf(whh4[3], h, A[3]);
        c = sigm(gfv) * c + sigm(gi) * tanh_f(gg);
        h = wave_sum_bcast(sigm(go) * tanh_f(c) * whr);
        const int t_out = dir ? (TLEN - 1 - f0 - s) : (f0 + s);
        if (lane == 0) h0p[(size_t)t_out * 2] = h;
#pragma unroll
        for (int k = 0; k < 4; ++k) A[k] = Nx[k];
    }
    if (lane == 0) hs[p] = h;
    cs[(size_t)p * 64 + lane] = c;
}

// ===========================================================================
// LSTM layer 1 (insz=2), 2-step x prefetch. One wave per (b,dir). DPP reduce.
// ===========================================================================
__global__ __launch_bounds__(256) void lstm1_kernel(
    const float* __restrict__ h0, const float* __restrict__ Wih,
    const float* __restrict__ Whh, const float* __restrict__ Whr,
    const float* __restrict__ bih, const float* __restrict__ bhh,
    float* __restrict__ h1)
{
    int w = threadIdx.x >> 6, lane = threadIdx.x & 63;
    int p = blockIdx.x * 4 + w;
    int b = p >> 1, dir = p & 1;

    float wi0[4], wi1[4], whh[4], bias[4];
#pragma unroll
    for (int k = 0; k < 4; ++k) {
        int r = k * 64 + lane;
        wi0[k] = Wih[(size_t)(dir * 256 + r) * 2 + 0];
        wi1[k] = Wih[(size_t)(dir * 256 + r) * 2 + 1];
        whh[k] = Whh[dir * 256 + r];
        bias[k] = bih[dir * 256 + r] + bhh[dir * 256 + r];
    }
    float whr = Whr[dir * HID + lane];
    float h = 0.0f, c = 0.0f;
    const float* hb = h0 + (size_t)b * TLEN * 2;

    auto xat = [&](int t) -> float2 {
        int tc = t < TLEN ? t : TLEN - 1;
        int tt = dir ? (TLEN - 1 - tc) : tc;
        return *(const float2*)(hb + (size_t)tt * 2);
    };

    float2 xA = xat(0), xB = xat(1);
    for (int t = 0; t < TLEN; t += 2) {
        float2 xC = xat(t + 2), xD = xat(t + 3);
        {
            float g[4];
#pragma unroll
            for (int k = 0; k < 4; ++k)
                g[k] = fmaf(whh[k], h, fmaf(wi1[k], xA.y, fmaf(wi0[k], xA.x, bias[k])));
            c = sigm(g[1]) * c + sigm(g[0]) * tanh_f(g[2]);
            h = wave_sum_bcast(sigm(g[3]) * tanh_f(c) * whr);
            int tt = dir ? (TLEN - 1 - t) : t;
            if (lane == 0) h1[((size_t)b * TLEN + tt) * 2 + dir] = h;
        }
        {
            float g[4];
#pragma unroll
            for (int k = 0; k < 4; ++k)
                g[k] = fmaf(whh[k], h, fmaf(wi1[k], xB.y, fmaf(wi0[k], xB.x, bias[k])));
            c = sigm(g[1]) * c + sigm(g[0]) * tanh_f(g[2]);
            h = wave_sum_bcast(sigm(g[3]) * tanh_f(c) * whr);
            int tt = dir ? (TLEN - 2 - t) : (t + 1);
            if (lane == 0) h1[((size_t)b * TLEN + tt) * 2 + dir] = h;
        }
        xA = xC; xB = xD;
    }
}

__global__ __launch_bounds__(256) void mean_kernel(
    const float2* __restrict__ h1, float* __restrict__ out)
{
    int i = blockIdx.x * 256 + threadIdx.x;
    if (i < BATCH * TLEN) {
        float2 v = h1[i];
        out[i] = 0.5f * (v.x + v.y);
    }
}

// ===========================================================================
extern "C" void kernel_launch(void* const* d_in, const int* in_sizes, int n_in,
                              void* d_out, int out_size, void* d_ws, size_t ws_size,
                              hipStream_t stream)
{
    const float* ccba_num = (const float*)d_in[0];
    const int*   ccba_bi  = (const int*)d_in[1];
    const int*   ccba_ti  = (const int*)d_in[2];
    const float* ccba_W   = (const float*)d_in[3];
    const float* ccba_b   = (const float*)d_in[4];
    const float* cdtx_num = (const float*)d_in[5];
    const int*   cdtx_cat = (const int*)d_in[6];
    const float* cdtx_tab = (const float*)d_in[7];
    const int*   cdtx_bi  = (const int*)d_in[8];
    const int*   cdtx_ti  = (const int*)d_in[9];
    const float* cdtx_W   = (const float*)d_in[10];
    const float* cdtx_b   = (const float*)d_in[11];
    const float* cust_num = (const float*)d_in[12];
    const int*   cust_cat = (const int*)d_in[13];
    const float* cust_tab = (const float*)d_in[14];
    const int*   cust_bi  = (const int*)d_in[15];
    const int*   cust_ti  = (const int*)d_in[16];
    const float* cust_W   = (const float*)d_in[17];
    const float* cust_b   = (const float*)d_in[18];
    const float* dp_num   = (const float*)d_in[19];
    const int*   dp_cat   = (const int*)d_in[20];
    const float* dp_tab   = (const float*)d_in[21];
    const int*   dp_bi    = (const int*)d_in[22];
    const int*   dp_ti    = (const int*)d_in[23];
    const float* dp_W     = (const float*)d_in[24];
    const float* dp_b     = (const float*)d_in[25];
    const float* remit_num = (const float*)d_in[26];
    const int*   remit_cat = (const int*)d_in[27];
    const float* remit_tab = (const float*)d_in[28];
    const int*   remit_bi  = (const int*)d_in[29];
    const int*   remit_ti  = (const int*)d_in[30];
    const float* remit_W   = (const float*)d_in[31];
    const float* remit_b   = (const float*)d_in[32];
    const float* Wih0 = (const float*)d_in[33];
    const float* Whh0 = (const float*)d_in[34];
    const float* Whr0 = (const float*)d_in[35];
    const float* bih0 = (const float*)d_in[36];
    const float* bhh0 = (const float*)d_in[37];
    const float* Wih1 = (const float*)d_in[38];
    const float* Whh1 = (const float*)d_in[39];
    const float* Whr1 = (const float*)d_in[40];
    const float* bih1 = (const float*)d_in[41];
    const float* bhh1 = (const float*)d_in[42];

    float* out = (float*)d_out;

    // Workspace layout (all sizes fixed except the two g_pre chunk buffers):
    //   gf  : 1000 * tcm * 256 * 4  (fwd-dir gate pre-activations, this chunk)
    //   gb  : same (bwd dir, mirrored time range)
    //   h0  : 1000*512*2*4 = 4,096,000
    //   h1  : 4,096,000
    //   wp  : 130*512*4 = 266,240
    //   hs  : 2000*4 = 8,000           (carried h state per (b,dir))
    //   cs  : 2000*64*4 = 512,000      (carried c state per (b,dir,cell))
    const size_t FIXED = 4096000ull + 4096000ull + 266240ull + 8000ull + 512000ull;
    size_t avail = (ws_size > FIXED) ? (ws_size - FIXED) : 0;
    int tcm = (int)(avail / 2048000ull);   // bytes per timestep across gf+gb
    if (tcm < 1) tcm = 1;
    if (tcm > TLEN) tcm = TLEN;

    char* ws = (char*)d_ws;
    const size_t gfB = (size_t)tcm * 1024000ull;
    float* gf = (float*)ws;
    float* gb = (float*)(ws + gfB);
    float* h0 = (float*)(ws + 2 * gfB);
    float* h1 = (float*)(ws + 2 * gfB + 4096000ull);
    float* wp = (float*)(ws + 2 * gfB + 8192000ull);
    float* hs = (float*)(ws + 2 * gfB + 8192000ull + 266240ull);
    float* cs = (float*)(ws + 2 * gfB + 8192000ull + 266240ull + 8000ull);

    compose_kernel<<<130, 512, 0, stream>>>(
        ccba_W, ccba_b, cdtx_W, cdtx_b, cust_W, cust_b,
        dp_W, dp_b, remit_W, remit_b, Wih0, bih0, bhh0, wp);

    int first = 1;
    for (int f0 = 0; f0 < TLEN; f0 += tcm) {
        const int len = (TLEN - f0 < tcm) ? (TLEN - f0) : tcm;
        project_chunk_kernel<<<dim3(256, 10), 256, 0, stream>>>(
            ccba_num, ccba_bi, ccba_ti,
            cdtx_num, cdtx_cat, cdtx_tab, cdtx_bi, cdtx_ti,
            cust_num, cust_cat, cust_tab, cust_bi, cust_ti,
            dp_num, dp_cat, dp_tab, dp_bi, dp_ti,
            remit_num, remit_cat, remit_tab, remit_bi, remit_ti,
            wp, gf, gb, f0, len, tcm);
        rec_chunk_kernel<<<500, 256, 0, stream>>>(
            gf, gb, Whh0, Whr0, h0, hs, cs, f0, len, tcm, first);
        first = 0;
    }

    lstm1_kernel<<<500, 256, 0, stream>>>(h0, Wih1, Whh1, Whr1, bih1, bhh1, h1);
    mean_kernel<<<(BATCH * TLEN + 255) / 256, 256, 0, stream>>>((const float2*)h1, out);
}